// Round 13
// baseline (462.281 us; speedup 1.0000x reference)
//
#include <hip/hip_runtime.h>
#include <hip/hip_bf16.h>

#define CC 16
#define LL 8192
#define SS 8191   // L-1
#define EE 512
#define HH 256
#define MM 128
#define TOPK 30
#define TOT (CC * SS)   // 131056 rows

typedef __attribute__((ext_vector_type(8))) short short8;
typedef __attribute__((ext_vector_type(4))) float f32x4;
typedef __attribute__((ext_vector_type(4))) unsigned int u32x4;

static __device__ __forceinline__ unsigned short f2bf(float f) {
    unsigned u = __builtin_bit_cast(unsigned, f);
    u += 0x7FFFu + ((u >> 16) & 1u);   // RNE
    return (unsigned short)(u >> 16);
}

static __device__ __forceinline__ unsigned pk2(float lo, float hi) {
    __hip_bfloat162 t = __float22bfloat162_rn(float2{lo, hi});
    unsigned u;
    __builtin_memcpy(&u, &t, 4);
    return u;
}

// 8 f32 -> 8 bf16 (v_cvt_pk_bf16_f32)
static __device__ __forceinline__ short8 cvt8(const float4 a, const float4 b) {
    u32x4 uv;
    uv[0] = pk2(a.x, a.y);
    uv[1] = pk2(a.z, a.w);
    uv[2] = pk2(b.x, b.y);
    uv[3] = pk2(b.z, b.w);
    return __builtin_bit_cast(short8, uv);
}

// ---- DPP row_ror reduces over 16-lane groups ----
template<int CTRL>
static __device__ __forceinline__ float dppf(float v) {
    return __builtin_bit_cast(float,
        __builtin_amdgcn_update_dpp(0, __builtin_bit_cast(int, v), CTRL, 0xF, 0xF, false));
}
template<int CTRL>
static __device__ __forceinline__ int dppi(int v) {
    return __builtin_amdgcn_update_dpp(0, v, CTRL, 0xF, 0xF, false);
}
static __device__ __forceinline__ float sum16f(float v) {
    v += dppf<0x121>(v); v += dppf<0x122>(v); v += dppf<0x124>(v); v += dppf<0x128>(v);
    return v;
}
static __device__ __forceinline__ float max16f(float v) {
    v = fmaxf(v, dppf<0x121>(v)); v = fmaxf(v, dppf<0x122>(v));
    v = fmaxf(v, dppf<0x124>(v)); v = fmaxf(v, dppf<0x128>(v));
    return v;
}
static __device__ __forceinline__ unsigned sum16u(unsigned v) {
    v += (unsigned)dppi<0x121>((int)v); v += (unsigned)dppi<0x122>((int)v);
    v += (unsigned)dppi<0x124>((int)v); v += (unsigned)dppi<0x128>((int)v);
    return v;
}

// ---------------- prep: W1 (E x H) -> W1T bf16 (H x E); W2 (H x M) -> W2T bf16 (M x H)
__global__ void prep_weights(const float* __restrict__ W1, const float* __restrict__ W2,
                             unsigned short* __restrict__ W1T, unsigned short* __restrict__ W2T)
{
    const int b = blockIdx.x, tid = threadIdx.x;
    if (b < 64) {
        const int e0 = b * 8, h = tid;
        short8 sv;
#pragma unroll
        for (int j = 0; j < 8; ++j)
            sv[j] = (short)f2bf(W1[(size_t)(e0 + j) * HH + h]);
        *(short8*)(void*)(W1T + (size_t)h * EE + e0) = sv;
    } else {
        const int h0 = (b - 64) * 16;
        if (tid < MM) {
            const int m = tid;
            short8 s0v, s1v;
#pragma unroll
            for (int j = 0; j < 8; ++j) {
                s0v[j] = (short)f2bf(W2[(size_t)(h0 + j) * MM + m]);
                s1v[j] = (short)f2bf(W2[(size_t)(h0 + 8 + j) * MM + m]);
            }
            *(short8*)(void*)(W2T + (size_t)m * HH + h0) = s0v;
            *(short8*)(void*)(W2T + (size_t)m * HH + h0 + 8) = s1v;
        }
    }
}

// ---------------- K1: GEMM-only, ZERO barriers. 256 threads = 4 independent waves.
// Each wave owns 16 rows + an 8KB private LDS slice:
//   [0,2K)+[2K,4K): x-chunk dbuf (16 rows x K=64 bf16, XOR-swizzled)
//   [0,8K) after GEMM1: h (16 rows x 256 bf16, XOR-swizzled)
// All LDS deps are wave-local (implicit lgkmcnt). Waves drift freely ->
// one wave's memory stall is hidden by the other ~15 resident waves (m114).
__global__ __launch_bounds__(256, 4)
void gene_gemm_kernel(const float* __restrict__ x,
                      const unsigned short* __restrict__ W1T,
                      const float* __restrict__ b1,
                      const unsigned short* __restrict__ W2T,
                      float* __restrict__ logits)
{
    __shared__ __align__(16) unsigned char lds[32768];

    const int tid  = threadIdx.x;
    const int c    = blockIdx.y;
    const int w    = tid >> 6;
    const int lane = tid & 63;
    const int lr   = lane & 15;
    const int kq   = lane >> 4;
    const int s0w  = blockIdx.x * 64 + w * 16;   // wave's 16 rows
    unsigned char* slice = lds + w * 8192;

    // staging map: lane -> row = lane>>2 (0..15), sq = lane&3 (64B contiguous/lane)
    const int srow = lane >> 2;
    const int sq   = lane & 3;
    const int rsc  = min(s0w + srow, SS - 1);
    const float* xrow = x + ((size_t)c * LL + 1 + rsc) * EE + sq * 16;
    unsigned char* wbase = slice + srow * 128;
    const int wswz = (srow & 7) << 4;
    const int rswz = (lr & 7) << 4;

    float4 xr0, xr1, xr2, xr3;
#define LOADX(ck) do { const float* p_ = xrow + (ck) * 64;                   \
    xr0 = *(const float4*)p_;       xr1 = *(const float4*)(p_ + 4);          \
    xr2 = *(const float4*)(p_ + 8); xr3 = *(const float4*)(p_ + 12); } while (0)

    f32x4 acc[16];
#pragma unroll
    for (int n = 0; n < 16; ++n) acc[n] = (f32x4)0.0f;

    LOADX(0);

    // ---- GEMM1: h[16][256] = relu(xs @ W1 + b1); 8 chunks of K=64, wave-local dbuf ----
#pragma unroll
    for (int ck = 0; ck < 8; ++ck) {
        const int bo = (ck & 1) << 11;   // 0 / 2048
        *(short8*)(void*)(wbase + bo + ((sq * 32 +  0) ^ wswz)) = cvt8(xr0, xr1);
        *(short8*)(void*)(wbase + bo + ((sq * 32 + 16) ^ wswz)) = cvt8(xr2, xr3);
        if (ck < 7) LOADX(ck + 1);   // next chunk's loads fly through this compute
#pragma unroll
        for (int ks = 0; ks < 2; ++ks) {
            const short8 af = *(const short8*)(const void*)
                (slice + bo + lr * 128 + ((ks * 64 + kq * 16) ^ rswz));
#pragma unroll
            for (int n = 0; n < 16; ++n) {
                const short8 bf_ = *(const short8*)(const void*)
                    (W1T + (size_t)(n * 16 + lr) * EE + ck * 64 + ks * 32 + kq * 8);
                acc[n] = __builtin_amdgcn_mfma_f32_16x16x32_bf16(af, bf_, acc[n], 0, 0, 0);
            }
        }
    }

    // ---- bias + relu -> h bf16 [16][512B] swizzled (overlays dbuf; wave-local) ----
#pragma unroll
    for (int n = 0; n < 16; ++n) {
        const float bb = b1[n * 16 + lr];
#pragma unroll
        for (int q = 0; q < 4; ++q) {
            const int row = kq * 4 + q;
            *(unsigned short*)(slice + row * 512 + (((n * 16 + lr) * 2) ^ ((row & 7) << 4))) =
                f2bf(fmaxf(acc[n][q] + bb, 0.0f));
        }
    }

    // ---- GEMM2: logits[16][128] = h @ W2 (wave-local) ----
    f32x4 acc2[8];
#pragma unroll
    for (int n = 0; n < 8; ++n) acc2[n] = (f32x4)0.0f;

#pragma unroll
    for (int ks = 0; ks < 8; ++ks) {
        const short8 ah = *(const short8*)(const void*)
            (slice + lr * 512 + ((ks * 64 + kq * 16) ^ rswz));
#pragma unroll
        for (int n = 0; n < 8; ++n) {
            const short8 bw = *(const short8*)(const void*)
                (W2T + (size_t)(n * 16 + lr) * HH + ks * 32 + kq * 8);
            acc2[n] = __builtin_amdgcn_mfma_f32_16x16x32_bf16(ah, bw, acc2[n], 0, 0, 0);
        }
    }

    // ---- direct global store of logits ----
#pragma unroll
    for (int n = 0; n < 8; ++n)
#pragma unroll
        for (int q = 0; q < 4; ++q) {
            const int s = s0w + kq * 4 + q;
            if (s < SS)
                logits[((size_t)c * SS + s) * MM + n * 16 + lr] = acc2[n][q];
        }
#undef LOADX
}

// ---------------- K2: epilogue-only. Barrier-free, LDS-free. 64 rows/block, 256 thr.
__global__ __launch_bounds__(256, 8)
void gene_epi_kernel(const float* __restrict__ noise,
                     const int*   __restrict__ mask,
                     const float* __restrict__ b2,
                     float* __restrict__ out,
                     float* __restrict__ outk)
{
    const int tid = threadIdx.x;
    const int tx  = tid & 15;
    const int ty  = tid >> 4;
    const long base = (long)blockIdx.x * 64;

    if (tid < 64) {
        const long gr = base + tid;
        if (gr < TOT) {
            const int cc2 = (int)(gr / SS);
            outk[gr] = (mask[gr + cc2 + 1] != 0) ? 1.0f : 0.0f;
        }
    }

    float b2v[8];
    {
        const float4 bb0 = *(const float4*)(b2 + tx * 8 + 0);
        const float4 bb1 = *(const float4*)(b2 + tx * 8 + 4);
        b2v[0]=bb0.x; b2v[1]=bb0.y; b2v[2]=bb0.z; b2v[3]=bb0.w;
        b2v[4]=bb1.x; b2v[5]=bb1.y; b2v[6]=bb1.z; b2v[7]=bb1.w;
    }

    float pr[4][8];
    float pmaxv[4];
    float mz[4];
    long  grv[4];

#pragma unroll
    for (int i = 0; i < 4; ++i) {
        const long gr  = base + ty * 4 + i;
        grv[i] = gr;
        const long grc = gr < TOT ? gr : (TOT - 1);
        const int  cc2 = (int)(grc / SS);
        mz[i] = (mask[grc + cc2 + 1] != 0) ? 0.0f : 1.0f;

        const float* lp = out   + grc * MM + tx * 8;
        const float* np = noise + grc * MM + tx * 8;
        const float4 l0 = *(const float4*)lp;
        const float4 l1 = *(const float4*)(lp + 4);
        const float4 u0 = *(const float4*)np;
        const float4 u1 = *(const float4*)(np + 4);
        const float lg[8] = {l0.x,l0.y,l0.z,l0.w,l1.x,l1.y,l1.z,l1.w};
        const float uu[8] = {u0.x,u0.y,u0.z,u0.w,u1.x,u1.y,u1.z,u1.w};
        float pm[8];
#pragma unroll
        for (int q = 0; q < 8; ++q) {
            const float g = -__logf(-__logf(uu[q] + 1e-20f) + 1e-20f);
            pm[q] = lg[q] + b2v[q] + g;
        }
        float mx = pm[0];
#pragma unroll
        for (int q = 1; q < 8; ++q) mx = fmaxf(mx, pm[q]);
        mx = max16f(mx);
        float se = 0.0f;
#pragma unroll
        for (int q = 0; q < 8; ++q) { pr[i][q] = __expf(pm[q] - mx); se += pr[i][q]; }
        se = sum16f(se);
        const float inv = 1.0f / se;
#pragma unroll
        for (int q = 0; q < 8; ++q) pr[i][q] *= inv;
        pmaxv[i] = inv;
    }

    float lo[4], hi[4];
#pragma unroll
    for (int i = 0; i < 4; ++i) { lo[i] = 0.0f; hi[i] = fminf(pmaxv[i], 1.0f / 30.0f); }
    for (int it = 0; it < 10; ++it) {
        float mid[4];
#pragma unroll
        for (int i = 0; i < 4; ++i) mid[i] = 0.5f * (lo[i] + hi[i]);
        unsigned cnt = 0;
#pragma unroll
        for (int q = 0; q < 8; ++q) {
            cnt += (pr[0][q] > mid[0]) ? 1u : 0u;
            cnt += (pr[1][q] > mid[1]) ? (1u << 8) : 0u;
            cnt += (pr[2][q] > mid[2]) ? (1u << 16) : 0u;
            cnt += (pr[3][q] > mid[3]) ? (1u << 24) : 0u;
        }
        cnt = sum16u(cnt);
#pragma unroll
        for (int i = 0; i < 4; ++i) {
            const bool ge = ((cnt >> (8 * i)) & 255u) >= TOPK;
            lo[i] = ge ? mid[i] : lo[i];
            hi[i] = ge ? hi[i] : mid[i];
        }
    }

#pragma unroll
    for (int i = 0; i < 4; ++i) {
        if (grv[i] < TOT) {
            float ov[8];
#pragma unroll
            for (int q = 0; q < 8; ++q) {
                const float sm = 1.0f / (1.0f + __expf((hi[i] - pr[i][q]) * 100.0f));
                ov[q] = pr[i][q] * sm * mz[i];
            }
            float* op = out + grv[i] * MM + tx * 8;
            float4 o0, o1;
            o0.x=ov[0]; o0.y=ov[1]; o0.z=ov[2]; o0.w=ov[3];
            o1.x=ov[4]; o1.y=ov[5]; o1.z=ov[6]; o1.w=ov[7];
            *(float4*)(op + 0) = o0;
            *(float4*)(op + 4) = o1;
        }
    }
}

extern "C" void kernel_launch(void* const* d_in, const int* in_sizes, int n_in,
                              void* d_out, int out_size, void* d_ws, size_t ws_size,
                              hipStream_t stream) {
    const float* x     = (const float*)d_in[0];
    const int*   mask  = (const int*)d_in[1];
    const float* noise = (const float*)d_in[2];
    const float* W1    = (const float*)d_in[3];
    const float* b1    = (const float*)d_in[4];
    const float* W2    = (const float*)d_in[5];
    const float* b2    = (const float*)d_in[6];
    float* out  = (float*)d_out;
    float* outk = out + (size_t)CC * SS * MM;

    unsigned short* W1T = (unsigned short*)d_ws;            // 256 x 512 bf16 = 256 KB
    unsigned short* W2T = W1T + (size_t)HH * EE;            // 128 x 256 bf16 =  64 KB

    prep_weights<<<dim3(80), dim3(256), 0, stream>>>(W1, W2, W1T, W2T);

    gene_gemm_kernel<<<dim3(128, CC), dim3(256), 0, stream>>>(x, W1T, b1, W2T, out);

    const int nblk = (TOT + 63) / 64;   // 2048
    gene_epi_kernel<<<dim3(nblk), dim3(256), 0, stream>>>(noise, mask, b2, out, outk);
}

// Round 15
// 295.713 us; speedup vs baseline: 1.5633x; 1.5633x over previous
//
#include <hip/hip_runtime.h>
#include <hip/hip_bf16.h>

#define CC 16
#define LL 8192
#define SS 8191   // L-1
#define EE 512
#define HH 256
#define MM 128
#define TOPK 30
#define TOT (CC * SS)   // 131056 rows

typedef __attribute__((ext_vector_type(8))) short short8;
typedef __attribute__((ext_vector_type(4))) float f32x4;
typedef __attribute__((ext_vector_type(4))) unsigned int u32x4;

static __device__ __forceinline__ unsigned short f2bf(float f) {
    unsigned u = __builtin_bit_cast(unsigned, f);
    u += 0x7FFFu + ((u >> 16) & 1u);   // RNE
    return (unsigned short)(u >> 16);
}

static __device__ __forceinline__ unsigned pk2(float lo, float hi) {
    __hip_bfloat162 t = __float22bfloat162_rn(float2{lo, hi});
    unsigned u;
    __builtin_memcpy(&u, &t, 4);
    return u;
}

// 8 f32 -> 8 bf16 (v_cvt_pk_bf16_f32)
static __device__ __forceinline__ short8 cvt8(const f32x4 a, const f32x4 b) {
    u32x4 uv;
    uv[0] = pk2(a[0], a[1]);
    uv[1] = pk2(a[2], a[3]);
    uv[2] = pk2(b[0], b[1]);
    uv[3] = pk2(b[2], b[3]);
    return __builtin_bit_cast(short8, uv);
}

// ---- DPP row_ror reduces over 16-lane groups ----
template<int CTRL>
static __device__ __forceinline__ float dppf(float v) {
    return __builtin_bit_cast(float,
        __builtin_amdgcn_update_dpp(0, __builtin_bit_cast(int, v), CTRL, 0xF, 0xF, false));
}
template<int CTRL>
static __device__ __forceinline__ int dppi(int v) {
    return __builtin_amdgcn_update_dpp(0, v, CTRL, 0xF, 0xF, false);
}
static __device__ __forceinline__ float sum16f(float v) {
    v += dppf<0x121>(v); v += dppf<0x122>(v); v += dppf<0x124>(v); v += dppf<0x128>(v);
    return v;
}
static __device__ __forceinline__ float max16f(float v) {
    v = fmaxf(v, dppf<0x121>(v)); v = fmaxf(v, dppf<0x122>(v));
    v = fmaxf(v, dppf<0x124>(v)); v = fmaxf(v, dppf<0x128>(v));
    return v;
}
static __device__ __forceinline__ unsigned sum16u(unsigned v) {
    v += (unsigned)dppi<0x121>((int)v); v += (unsigned)dppi<0x122>((int)v);
    v += (unsigned)dppi<0x124>((int)v); v += (unsigned)dppi<0x128>((int)v);
    return v;
}

// lgkm-only barrier: NO vmcnt drain
static __device__ __forceinline__ void bar_lgkm() {
    asm volatile("s_waitcnt lgkmcnt(0)" ::: "memory");
    __builtin_amdgcn_sched_barrier(0);
    __builtin_amdgcn_s_barrier();
    __builtin_amdgcn_sched_barrier(0);
}

// ---------------- prep: W1 (E x H) -> W1T bf16 (H x E); W2 (H x M) -> W2T bf16 (M x H)
__global__ void prep_weights(const float* __restrict__ W1, const float* __restrict__ W2,
                             unsigned short* __restrict__ W1T, unsigned short* __restrict__ W2T)
{
    const int b = blockIdx.x, tid = threadIdx.x;
    if (b < 64) {
        const int e0 = b * 8, h = tid;
        short8 sv;
#pragma unroll
        for (int j = 0; j < 8; ++j)
            sv[j] = (short)f2bf(W1[(size_t)(e0 + j) * HH + h]);
        *(short8*)(void*)(W1T + (size_t)h * EE + e0) = sv;
    } else {
        const int h0 = (b - 64) * 16;
        if (tid < MM) {
            const int m = tid;
            short8 s0v, s1v;
#pragma unroll
            for (int j = 0; j < 8; ++j) {
                s0v[j] = (short)f2bf(W2[(size_t)(h0 + j) * MM + m]);
                s1v[j] = (short)f2bf(W2[(size_t)(h0 + 8 + j) * MM + m]);
            }
            *(short8*)(void*)(W2T + (size_t)m * HH + h0) = s0v;
            *(short8*)(void*)(W2T + (size_t)m * HH + h0 + 8) = s1v;
        }
    }
}

// ---------------- K1a: h = relu(x @ W1 + b1), bf16, written into the out buffer.
// 64 rows/block, 512 threads (8 waves = 2 row-groups x 4 col-groups).
// LDS = 16 KB staging dbuf only. Reg-staged, lgkm-only barriers, NT x loads.
__global__ __launch_bounds__(512, 6)
void gene_h_kernel(const float* __restrict__ x,
                   const unsigned short* __restrict__ W1T,
                   const float* __restrict__ b1,
                   unsigned short* __restrict__ hb)   // h bf16 [TOT][256] (= out bytes)
{
    __shared__ __align__(16) unsigned char lds[16384];

    const int tid  = threadIdx.x;
    const int c    = blockIdx.y;
    const int s0   = blockIdx.x * 64;

    const int w    = tid >> 6;
    const int lane = tid & 63;
    const int lr   = lane & 15;
    const int kq   = lane >> 4;
    const int wr   = w >> 2;        // 0..1: rows wr*32..+31
    const int wc   = w & 3;         // 0..3: cols wc*64..+63
    const int cw   = wc * 64;

    // staging map: thread -> row = tid>>3 (0..63), sk = tid&7 (8 f32 slice)
    const int srow = tid >> 3;
    const int sk   = tid & 7;
    const int rsc  = min(s0 + srow, SS - 1);
    const float* xrow = x + ((size_t)c * LL + 1 + rsc) * EE + sk * 8;
    unsigned char* wbase = lds + srow * 128;
    const int wswz = (srow & 7) << 4;

    f32x4 xr0, xr1;
#define LOADX(ck) do { const f32x4* p_ = (const f32x4*)(xrow + (ck) * 64);    \
    xr0 = __builtin_nontemporal_load(p_);                                     \
    xr1 = __builtin_nontemporal_load(p_ + 1); } while (0)

    float b1v[4];
#pragma unroll
    for (int n = 0; n < 4; ++n) b1v[n] = b1[cw + n * 16 + lr];

    f32x4 acc[2][4];
#pragma unroll
    for (int r = 0; r < 2; ++r)
#pragma unroll
        for (int n = 0; n < 4; ++n) acc[r][n] = (f32x4)0.0f;

    LOADX(0);

#pragma unroll
    for (int ck = 0; ck < 8; ++ck) {
        const int bo = (ck & 1) << 13;   // 0 / 8192
        *(short8*)(void*)(wbase + bo + ((sk * 16) ^ wswz)) = cvt8(xr0, xr1);
        if (ck < 7) LOADX(ck + 1);
        bar_lgkm();

#pragma unroll
        for (int ks = 0; ks < 2; ++ks) {
            short8 af[2];
#pragma unroll
            for (int r = 0; r < 2; ++r) {
                const int row = wr * 32 + r * 16 + lr;
                af[r] = *(const short8*)(const void*)
                    (lds + bo + row * 128 + ((ks * 64 + kq * 16) ^ ((row & 7) << 4)));
            }
#pragma unroll
            for (int n = 0; n < 4; ++n) {
                const short8 bf_ = *(const short8*)(const void*)
                    (W1T + (size_t)(cw + n * 16 + lr) * EE + ck * 64 + ks * 32 + kq * 8);
#pragma unroll
                for (int r = 0; r < 2; ++r)
                    acc[r][n] = __builtin_amdgcn_mfma_f32_16x16x32_bf16(af[r], bf_, acc[r][n], 0, 0, 0);
            }
        }
        bar_lgkm();
    }

    // ---- bias + relu -> h bf16, NT scalar stores ----
#pragma unroll
    for (int n = 0; n < 4; ++n) {
        const int col = cw + n * 16 + lr;
#pragma unroll
        for (int r = 0; r < 2; ++r)
#pragma unroll
            for (int q = 0; q < 4; ++q) {
                const int s = s0 + wr * 32 + r * 16 + kq * 4 + q;
                if (s < SS) {
                    const unsigned short hv = f2bf(fmaxf(acc[r][n][q] + b1v[n], 0.0f));
                    __builtin_nontemporal_store(hv, hb + ((size_t)c * SS + s) * HH + col);
                }
            }
    }
#undef LOADX
}

// ---------------- K1b: logits = h @ W2 + full epilogue, in place over h bytes.
// 64 rows/block, 256 threads (4 col-waves). LDS: h stage 32KB -> logits f32 [64][132].
__global__ __launch_bounds__(256, 4)
void gene_out_kernel(const unsigned short* __restrict__ hb,
                     const float* __restrict__ noise,
                     const int*   __restrict__ mask,
                     const unsigned short* __restrict__ W2T,
                     const float* __restrict__ b2,
                     float* __restrict__ out,
                     float* __restrict__ outk)
{
    __shared__ __align__(16) unsigned char lds[33792];
    float* sLf = (float*)lds;

    const int tid  = threadIdx.x;
    const long base = (long)blockIdx.x * 64;
    const int lane = tid & 63;
    const int lr   = lane & 15;
    const int kq   = lane >> 4;
    const int wc   = tid >> 6;      // wave = col quarter
    const int tx   = tid & 15;
    const int ty   = tid >> 4;

    if (tid < 64) {
        const long gr = base + tid;
        if (gr < TOT) {
            const int cc2 = (int)(gr / SS);
            outk[gr] = (mask[gr + cc2 + 1] != 0) ? 1.0f : 0.0f;
        }
    }

    // ---- stage h [64 rows][256 bf16] -> LDS swizzled; NT loads ----
    {
        const int row = tid >> 2;           // 0..63
        const int skq = tid & 3;            // 128B quarter of the row
        const long grc = min(base + row, (long)TOT - 1);
        const unsigned short* hrow = hb + grc * HH + skq * 64;
        unsigned char* wb = lds + row * 512;
        const int swz = (row & 7) << 4;
#pragma unroll
        for (int u = 0; u < 8; ++u) {
            const short8 v = __builtin_nontemporal_load((const short8*)(const void*)(hrow + u * 8));
            *(short8*)(void*)(wb + (((skq * 8 + u) * 16) ^ swz)) = v;
        }
    }
    __syncthreads();

    // ---- GEMM2: logits[64][128] = h @ W2 ----
    f32x4 acc2[4][2];
#pragma unroll
    for (int r = 0; r < 4; ++r)
#pragma unroll
        for (int n = 0; n < 2; ++n) acc2[r][n] = (f32x4)0.0f;

    const int cw2 = wc * 32;
#pragma unroll
    for (int ks = 0; ks < 8; ++ks) {
        short8 ah[4];
#pragma unroll
        for (int r = 0; r < 4; ++r) {
            const int row = r * 16 + lr;
            ah[r] = *(const short8*)(const void*)
                (lds + row * 512 + ((ks * 64 + kq * 16) ^ ((row & 7) << 4)));
        }
        short8 bw[2];
#pragma unroll
        for (int n = 0; n < 2; ++n)
            bw[n] = *(const short8*)(const void*)
                (W2T + (size_t)(cw2 + n * 16 + lr) * HH + ks * 32 + kq * 8);
#pragma unroll
        for (int r = 0; r < 4; ++r)
#pragma unroll
            for (int n = 0; n < 2; ++n)
                acc2[r][n] = __builtin_amdgcn_mfma_f32_16x16x32_bf16(ah[r], bw[n], acc2[r][n], 0, 0, 0);
    }
    __syncthreads();   // all h reads done; overlay logits

    // ---- logits -> sLf [64][132] ----
#pragma unroll
    for (int r = 0; r < 4; ++r)
#pragma unroll
        for (int n = 0; n < 2; ++n)
#pragma unroll
            for (int q = 0; q < 4; ++q) {
                const int row = r * 16 + kq * 4 + q;
                const int col = cw2 + n * 16 + lr;
                sLf[row * 132 + col] = acc2[r][n][q];
            }
    __syncthreads();

    // ---- epilogue (proven K2 structure) ----
    float b2v[8];
    {
        const float4 bb0 = *(const float4*)(b2 + tx * 8 + 0);
        const float4 bb1 = *(const float4*)(b2 + tx * 8 + 4);
        b2v[0]=bb0.x; b2v[1]=bb0.y; b2v[2]=bb0.z; b2v[3]=bb0.w;
        b2v[4]=bb1.x; b2v[5]=bb1.y; b2v[6]=bb1.z; b2v[7]=bb1.w;
    }

    float pr[4][8];
    float pmaxv[4];
    float mz[4];
    long  grv[4];

#pragma unroll
    for (int i = 0; i < 4; ++i) {
        const int row = ty * 4 + i;
        const long gr = base + row;
        grv[i] = gr;
        const long grc = gr < TOT ? gr : (TOT - 1);
        const int  cc2 = (int)(grc / SS);
        mz[i] = (mask[grc + cc2 + 1] != 0) ? 0.0f : 1.0f;

        const f32x4* np = (const f32x4*)(noise + grc * MM + tx * 8);
        const f32x4 u0 = __builtin_nontemporal_load(np);
        const f32x4 u1 = __builtin_nontemporal_load(np + 1);
        const float4 l0 = *(const float4*)&sLf[row * 132 + tx * 8];
        const float4 l1 = *(const float4*)&sLf[row * 132 + tx * 8 + 4];
        const float lg[8] = {l0.x,l0.y,l0.z,l0.w,l1.x,l1.y,l1.z,l1.w};
        const float uu[8] = {u0[0],u0[1],u0[2],u0[3],u1[0],u1[1],u1[2],u1[3]};
        float pm[8];
#pragma unroll
        for (int q = 0; q < 8; ++q) {
            const float g = -__logf(-__logf(uu[q] + 1e-20f) + 1e-20f);
            pm[q] = lg[q] + b2v[q] + g;
        }
        float mx = pm[0];
#pragma unroll
        for (int q = 1; q < 8; ++q) mx = fmaxf(mx, pm[q]);
        mx = max16f(mx);
        float se = 0.0f;
#pragma unroll
        for (int q = 0; q < 8; ++q) { pr[i][q] = __expf(pm[q] - mx); se += pr[i][q]; }
        se = sum16f(se);
        const float inv = 1.0f / se;
#pragma unroll
        for (int q = 0; q < 8; ++q) pr[i][q] *= inv;
        pmaxv[i] = inv;
    }

    float lo[4], hi[4];
#pragma unroll
    for (int i = 0; i < 4; ++i) { lo[i] = 0.0f; hi[i] = fminf(pmaxv[i], 1.0f / 30.0f); }
    for (int it = 0; it < 10; ++it) {
        float mid[4];
#pragma unroll
        for (int i = 0; i < 4; ++i) mid[i] = 0.5f * (lo[i] + hi[i]);
        unsigned cnt = 0;
#pragma unroll
        for (int q = 0; q < 8; ++q) {
            cnt += (pr[0][q] > mid[0]) ? 1u : 0u;
            cnt += (pr[1][q] > mid[1]) ? (1u << 8) : 0u;
            cnt += (pr[2][q] > mid[2]) ? (1u << 16) : 0u;
            cnt += (pr[3][q] > mid[3]) ? (1u << 24) : 0u;
        }
        cnt = sum16u(cnt);
#pragma unroll
        for (int i = 0; i < 4; ++i) {
            const bool ge = ((cnt >> (8 * i)) & 255u) >= TOPK;
            lo[i] = ge ? mid[i] : lo[i];
            hi[i] = ge ? hi[i] : mid[i];
        }
    }

#pragma unroll
    for (int i = 0; i < 4; ++i) {
        if (grv[i] < TOT) {
            float ov[8];
#pragma unroll
            for (int q = 0; q < 8; ++q) {
                const float sm = 1.0f / (1.0f + __expf((hi[i] - pr[i][q]) * 100.0f));
                ov[q] = pr[i][q] * sm * mz[i];
            }
            f32x4* op = (f32x4*)(out + grv[i] * MM + tx * 8);
            f32x4 o0, o1;
            o0[0]=ov[0]; o0[1]=ov[1]; o0[2]=ov[2]; o0[3]=ov[3];
            o1[0]=ov[4]; o1[1]=ov[5]; o1[2]=ov[6]; o1[3]=ov[7];
            __builtin_nontemporal_store(o0, op);
            __builtin_nontemporal_store(o1, op + 1);
        }
    }
}

extern "C" void kernel_launch(void* const* d_in, const int* in_sizes, int n_in,
                              void* d_out, int out_size, void* d_ws, size_t ws_size,
                              hipStream_t stream) {
    const float* x     = (const float*)d_in[0];
    const int*   mask  = (const int*)d_in[1];
    const float* noise = (const float*)d_in[2];
    const float* W1    = (const float*)d_in[3];
    const float* b1    = (const float*)d_in[4];
    const float* W2    = (const float*)d_in[5];
    const float* b2    = (const float*)d_in[6];
    float* out  = (float*)d_out;
    float* outk = out + (size_t)CC * SS * MM;

    unsigned short* W1T = (unsigned short*)d_ws;            // 256 x 512 bf16 = 256 KB
    unsigned short* W2T = W1T + (size_t)HH * EE;            // 128 x 256 bf16 =  64 KB
    unsigned short* hb  = (unsigned short*)d_out;           // h bf16 aliases out bytes

    prep_weights<<<dim3(80), dim3(256), 0, stream>>>(W1, W2, W1T, W2T);

    gene_h_kernel<<<dim3(128, CC), dim3(512), 0, stream>>>(x, W1T, b1, hb);

    gene_out_kernel<<<dim3(2048), dim3(256), 0, stream>>>(hb, noise, mask, W2T, b2, out, outk);
}

// Round 16
// 247.830 us; speedup vs baseline: 1.8653x; 1.1932x over previous
//
#include <hip/hip_runtime.h>
#include <hip/hip_bf16.h>

#define CC 16
#define LL 8192
#define SS 8191   // L-1
#define EE 512
#define HH 256
#define MM 128
#define TOPK 30
#define TOT (CC * SS)   // 131056 rows

typedef __attribute__((ext_vector_type(8))) short short8;
typedef __attribute__((ext_vector_type(4))) float f32x4;
typedef __attribute__((ext_vector_type(4))) unsigned int u32x4;

static __device__ __forceinline__ unsigned short f2bf(float f) {
    unsigned u = __builtin_bit_cast(unsigned, f);
    u += 0x7FFFu + ((u >> 16) & 1u);   // RNE
    return (unsigned short)(u >> 16);
}

static __device__ __forceinline__ unsigned pk2(float lo, float hi) {
    __hip_bfloat162 t = __float22bfloat162_rn(float2{lo, hi});
    unsigned u;
    __builtin_memcpy(&u, &t, 4);
    return u;
}

// 8 f32 -> 8 bf16 (v_cvt_pk_bf16_f32)
static __device__ __forceinline__ short8 cvt8(const f32x4 a, const f32x4 b) {
    u32x4 uv;
    uv[0] = pk2(a[0], a[1]);
    uv[1] = pk2(a[2], a[3]);
    uv[2] = pk2(b[0], b[1]);
    uv[3] = pk2(b[2], b[3]);
    return __builtin_bit_cast(short8, uv);
}

// ---- DPP row_ror reduces over 16-lane groups ----
template<int CTRL>
static __device__ __forceinline__ float dppf(float v) {
    return __builtin_bit_cast(float,
        __builtin_amdgcn_update_dpp(0, __builtin_bit_cast(int, v), CTRL, 0xF, 0xF, false));
}
template<int CTRL>
static __device__ __forceinline__ int dppi(int v) {
    return __builtin_amdgcn_update_dpp(0, v, CTRL, 0xF, 0xF, false);
}
static __device__ __forceinline__ float sum16f(float v) {
    v += dppf<0x121>(v); v += dppf<0x122>(v); v += dppf<0x124>(v); v += dppf<0x128>(v);
    return v;
}
static __device__ __forceinline__ float max16f(float v) {
    v = fmaxf(v, dppf<0x121>(v)); v = fmaxf(v, dppf<0x122>(v));
    v = fmaxf(v, dppf<0x124>(v)); v = fmaxf(v, dppf<0x128>(v));
    return v;
}
static __device__ __forceinline__ unsigned sum16u(unsigned v) {
    v += (unsigned)dppi<0x121>((int)v); v += (unsigned)dppi<0x122>((int)v);
    v += (unsigned)dppi<0x124>((int)v); v += (unsigned)dppi<0x128>((int)v);
    return v;
}

// lgkm-only barrier: NO vmcnt drain
static __device__ __forceinline__ void bar_lgkm() {
    asm volatile("s_waitcnt lgkmcnt(0)" ::: "memory");
    __builtin_amdgcn_sched_barrier(0);
    __builtin_amdgcn_s_barrier();
    __builtin_amdgcn_sched_barrier(0);
}

// ---------------- prep: W1 (E x H) -> W1T bf16 (H x E); W2 (H x M) -> W2T bf16 (M x H)
__global__ void prep_weights(const float* __restrict__ W1, const float* __restrict__ W2,
                             unsigned short* __restrict__ W1T, unsigned short* __restrict__ W2T)
{
    const int b = blockIdx.x, tid = threadIdx.x;
    if (b < 64) {
        const int e0 = b * 8, h = tid;
        short8 sv;
#pragma unroll
        for (int j = 0; j < 8; ++j)
            sv[j] = (short)f2bf(W1[(size_t)(e0 + j) * HH + h]);
        *(short8*)(void*)(W1T + (size_t)h * EE + e0) = sv;
    } else {
        const int h0 = (b - 64) * 16;
        if (tid < MM) {
            const int m = tid;
            short8 s0v, s1v;
#pragma unroll
            for (int j = 0; j < 8; ++j) {
                s0v[j] = (short)f2bf(W2[(size_t)(h0 + j) * MM + m]);
                s1v[j] = (short)f2bf(W2[(size_t)(h0 + 8 + j) * MM + m]);
            }
            *(short8*)(void*)(W2T + (size_t)m * HH + h0) = s0v;
            *(short8*)(void*)(W2T + (size_t)m * HH + h0 + 8) = s1v;
        }
    }
}

// ---------------- K1: fused GEMM (R12 structure), logits -> out.
// 128 rows/block, 512 threads (8 waves, 2Mrow x 4Ncol). Reg-staged bf16 x,
// lgkm-only barriers. NEW: per chunk, W-frag burst issued BEFORE the x prefetch,
// so MFMA's vmcnt wait (for W) leaves x(ck+1) in flight across the barrier.
__global__ __launch_bounds__(512, 4)
void gene_gemm_kernel(const float* __restrict__ x,
                      const unsigned short* __restrict__ W1T,
                      const float* __restrict__ b1,
                      const unsigned short* __restrict__ W2T,
                      float* __restrict__ logits)
{
    __shared__ __align__(16) unsigned char lds[65536];

    const int tid = threadIdx.x;
    const int c   = blockIdx.y;
    const int s0  = blockIdx.x * 128;

    const int w    = tid >> 6;
    const int lane = tid & 63;
    const int lr   = lane & 15;
    const int kq   = lane >> 4;
    const int wr   = w >> 2;
    const int wc   = w & 3;
    const int cw   = wc * 64;

    // staging mapping: thread -> (row, 16-f32 k-slice); fully coalesced per row
    const int srow = tid >> 2;              // 0..127
    const int sk4  = tid & 3;               // k-slice quarter
    const int rsc  = min(s0 + srow, SS - 1) - s0;
    const float* xrow = x + ((size_t)c * LL + s0 + 1 + rsc) * EE + sk4 * 16;
    const int swz = (srow & 7) << 4;
    unsigned char* wb = lds + srow * 128;

    f32x4 xr0, xr1, xr2, xr3;
#define LOADX(ck) do { const f32x4* p_ = (const f32x4*)(xrow + (ck) * 64);    \
    xr0 = __builtin_nontemporal_load(p_);                                     \
    xr1 = __builtin_nontemporal_load(p_ + 1);                                 \
    xr2 = __builtin_nontemporal_load(p_ + 2);                                 \
    xr3 = __builtin_nontemporal_load(p_ + 3); } while (0)

    f32x4 acc[4][4];
#pragma unroll
    for (int r = 0; r < 4; ++r)
#pragma unroll
        for (int n = 0; n < 4; ++n) acc[r][n] = (f32x4)0.0f;

    LOADX(0);

    short8 wf[2][4];   // current chunk's W frags (both k-steps)

#pragma unroll
    for (int ck = 0; ck < 8; ++ck) {
        const int bo = (ck & 1) << 14;
        // 1. stage chunk ck (regs -> bf16 LDS); waits only on xr (oldest VMEM)
        *(short8*)(void*)(wb + bo + (((sk4 * 2 + 0) * 16) ^ swz)) = cvt8(xr0, xr1);
        *(short8*)(void*)(wb + bo + (((sk4 * 2 + 1) * 16) ^ swz)) = cvt8(xr2, xr3);
        // 2. W burst for chunk ck — issued BEFORE x(ck+1) so W's waits don't drain it
#pragma unroll
        for (int ks = 0; ks < 2; ++ks)
#pragma unroll
            for (int n = 0; n < 4; ++n)
                wf[ks][n] = *(const short8*)(const void*)
                    (W1T + (size_t)(cw + n * 16 + lr) * EE + ck * 64 + ks * 32 + kq * 8);
        __builtin_amdgcn_sched_barrier(0);
        // 3. x prefetch LAST (youngest in FIFO -> survives W waits)
        if (ck < 7) LOADX(ck + 1);
        // 4. barrier (lgkm-only)
        bar_lgkm();

        // 5. compute chunk ck
#pragma unroll
        for (int ks = 0; ks < 2; ++ks) {
            short8 af[4];
#pragma unroll
            for (int r = 0; r < 4; ++r) {
                const int row = wr * 64 + r * 16 + lr;
                af[r] = *(const short8*)(const void*)
                    (lds + bo + row * 128 + (((ks * 4 + kq) * 16) ^ ((row & 7) << 4)));
            }
#pragma unroll
            for (int r = 0; r < 4; ++r)
#pragma unroll
                for (int n = 0; n < 4; ++n)
                    acc[r][n] = __builtin_amdgcn_mfma_f32_16x16x32_bf16(af[r], wf[ks][n], acc[r][n], 0, 0, 0);
        }
        bar_lgkm();   // all reads of buf[ck&1] done before iter ck+2 overwrites it
    }

    // ---- bias + relu -> h bf16 [128][256] swizzled (overlays staging) ----
    float b1v[4];
#pragma unroll
    for (int n = 0; n < 4; ++n) b1v[n] = b1[cw + n * 16 + lr];

#pragma unroll
    for (int n = 0; n < 4; ++n) {
        const int colh = cw + n * 16 + lr;
#pragma unroll
        for (int r = 0; r < 4; ++r)
#pragma unroll
            for (int q = 0; q < 4; ++q) {
                const int row = wr * 64 + r * 16 + kq * 4 + q;
                *(unsigned short*)(lds + row * 512 + ((colh * 2) ^ ((row & 7) << 4))) =
                    f2bf(fmaxf(acc[r][n][q] + b1v[n], 0.0f));
            }
    }
    bar_lgkm();

    // ---- GEMM2: logits[128][128] = h @ W2 ----
    f32x4 acc2[4][2];
#pragma unroll
    for (int r = 0; r < 4; ++r)
#pragma unroll
        for (int n = 0; n < 2; ++n) acc2[r][n] = (f32x4)0.0f;

    const int cw2 = wc * 32;
#pragma unroll 4
    for (int ks = 0; ks < 8; ++ks) {
        short8 ah[4];
#pragma unroll
        for (int r = 0; r < 4; ++r) {
            const int row = wr * 64 + r * 16 + lr;
            ah[r] = *(const short8*)(const void*)
                (lds + row * 512 + ((ks * 64 + kq * 16) ^ ((row & 7) << 4)));
        }
        short8 bw[2];
#pragma unroll
        for (int n = 0; n < 2; ++n)
            bw[n] = *(const short8*)(const void*)
                (W2T + (size_t)(cw2 + n * 16 + lr) * HH + ks * 32 + kq * 8);
#pragma unroll
        for (int r = 0; r < 4; ++r)
#pragma unroll
            for (int n = 0; n < 2; ++n)
                acc2[r][n] = __builtin_amdgcn_mfma_f32_16x16x32_bf16(ah[r], bw[n], acc2[r][n], 0, 0, 0);
    }

    // ---- direct global store of logits ----
#pragma unroll
    for (int r = 0; r < 4; ++r)
#pragma unroll
        for (int n = 0; n < 2; ++n)
#pragma unroll
            for (int q = 0; q < 4; ++q) {
                const int s = s0 + wr * 64 + r * 16 + kq * 4 + q;
                if (s < SS)
                    logits[((size_t)c * SS + s) * MM + cw2 + n * 16 + lr] = acc2[r][n][q];
            }
#undef LOADX
}

// ---------------- K2: epilogue-only. Barrier-free, LDS-free. 64 rows/block, 256 thr.
__global__ __launch_bounds__(256, 8)
void gene_epi_kernel(const float* __restrict__ noise,
                     const int*   __restrict__ mask,
                     const float* __restrict__ b2,
                     float* __restrict__ out,
                     float* __restrict__ outk)
{
    const int tid = threadIdx.x;
    const int tx  = tid & 15;
    const int ty  = tid >> 4;
    const long base = (long)blockIdx.x * 64;

    if (tid < 64) {
        const long gr = base + tid;
        if (gr < TOT) {
            const int cc2 = (int)(gr / SS);
            outk[gr] = (mask[gr + cc2 + 1] != 0) ? 1.0f : 0.0f;
        }
    }

    float b2v[8];
    {
        const float4 bb0 = *(const float4*)(b2 + tx * 8 + 0);
        const float4 bb1 = *(const float4*)(b2 + tx * 8 + 4);
        b2v[0]=bb0.x; b2v[1]=bb0.y; b2v[2]=bb0.z; b2v[3]=bb0.w;
        b2v[4]=bb1.x; b2v[5]=bb1.y; b2v[6]=bb1.z; b2v[7]=bb1.w;
    }

    float pr[4][8];
    float pmaxv[4];
    float mz[4];
    long  grv[4];

#pragma unroll
    for (int i = 0; i < 4; ++i) {
        const long gr  = base + ty * 4 + i;
        grv[i] = gr;
        const long grc = gr < TOT ? gr : (TOT - 1);
        const int  cc2 = (int)(grc / SS);
        mz[i] = (mask[grc + cc2 + 1] != 0) ? 0.0f : 1.0f;

        const float* lp = out   + grc * MM + tx * 8;
        const float* np = noise + grc * MM + tx * 8;
        const float4 l0 = *(const float4*)lp;
        const float4 l1 = *(const float4*)(lp + 4);
        const float4 u0 = *(const float4*)np;
        const float4 u1 = *(const float4*)(np + 4);
        const float lg[8] = {l0.x,l0.y,l0.z,l0.w,l1.x,l1.y,l1.z,l1.w};
        const float uu[8] = {u0.x,u0.y,u0.z,u0.w,u1.x,u1.y,u1.z,u1.w};
        float pm[8];
#pragma unroll
        for (int q = 0; q < 8; ++q) {
            const float g = -__logf(-__logf(uu[q] + 1e-20f) + 1e-20f);
            pm[q] = lg[q] + b2v[q] + g;
        }
        float mx = pm[0];
#pragma unroll
        for (int q = 1; q < 8; ++q) mx = fmaxf(mx, pm[q]);
        mx = max16f(mx);
        float se = 0.0f;
#pragma unroll
        for (int q = 0; q < 8; ++q) { pr[i][q] = __expf(pm[q] - mx); se += pr[i][q]; }
        se = sum16f(se);
        const float inv = 1.0f / se;
#pragma unroll
        for (int q = 0; q < 8; ++q) pr[i][q] *= inv;
        pmaxv[i] = inv;
    }

    float lo[4], hi[4];
#pragma unroll
    for (int i = 0; i < 4; ++i) { lo[i] = 0.0f; hi[i] = fminf(pmaxv[i], 1.0f / 30.0f); }
    for (int it = 0; it < 10; ++it) {
        float mid[4];
#pragma unroll
        for (int i = 0; i < 4; ++i) mid[i] = 0.5f * (lo[i] + hi[i]);
        unsigned cnt = 0;
#pragma unroll
        for (int q = 0; q < 8; ++q) {
            cnt += (pr[0][q] > mid[0]) ? 1u : 0u;
            cnt += (pr[1][q] > mid[1]) ? (1u << 8) : 0u;
            cnt += (pr[2][q] > mid[2]) ? (1u << 16) : 0u;
            cnt += (pr[3][q] > mid[3]) ? (1u << 24) : 0u;
        }
        cnt = sum16u(cnt);
#pragma unroll
        for (int i = 0; i < 4; ++i) {
            const bool ge = ((cnt >> (8 * i)) & 255u) >= TOPK;
            lo[i] = ge ? mid[i] : lo[i];
            hi[i] = ge ? hi[i] : mid[i];
        }
    }

#pragma unroll
    for (int i = 0; i < 4; ++i) {
        if (grv[i] < TOT) {
            float ov[8];
#pragma unroll
            for (int q = 0; q < 8; ++q) {
                const float sm = 1.0f / (1.0f + __expf((hi[i] - pr[i][q]) * 100.0f));
                ov[q] = pr[i][q] * sm * mz[i];
            }
            float* op = out + grv[i] * MM + tx * 8;
            float4 o0, o1;
            o0.x=ov[0]; o0.y=ov[1]; o0.z=ov[2]; o0.w=ov[3];
            o1.x=ov[4]; o1.y=ov[5]; o1.z=ov[6]; o1.w=ov[7];
            *(float4*)(op + 0) = o0;
            *(float4*)(op + 4) = o1;
        }
    }
}

extern "C" void kernel_launch(void* const* d_in, const int* in_sizes, int n_in,
                              void* d_out, int out_size, void* d_ws, size_t ws_size,
                              hipStream_t stream) {
    const float* x     = (const float*)d_in[0];
    const int*   mask  = (const int*)d_in[1];
    const float* noise = (const float*)d_in[2];
    const float* W1    = (const float*)d_in[3];
    const float* b1    = (const float*)d_in[4];
    const float* W2    = (const float*)d_in[5];
    const float* b2    = (const float*)d_in[6];
    float* out  = (float*)d_out;
    float* outk = out + (size_t)CC * SS * MM;

    unsigned short* W1T = (unsigned short*)d_ws;            // 256 x 512 bf16 = 256 KB
    unsigned short* W2T = W1T + (size_t)HH * EE;            // 128 x 256 bf16 =  64 KB

    prep_weights<<<dim3(80), dim3(256), 0, stream>>>(W1, W2, W1T, W2T);

    gene_gemm_kernel<<<dim3(64, CC), dim3(512), 0, stream>>>(x, W1T, b1, W2T, out);

    const int nblk = (TOT + 63) / 64;   // 2048
    gene_epi_kernel<<<dim3(nblk), dim3(256), 0, stream>>>(noise, mask, b2, out, outk);
}

// Round 17
// 180.325 us; speedup vs baseline: 2.5636x; 1.3744x over previous
//
#include <hip/hip_runtime.h>
#include <hip/hip_bf16.h>

#define CC 16
#define LL 8192
#define SS 8191   // L-1
#define EE 512
#define HH 256
#define MM 128
#define TOPK 30
#define TOT (CC * SS)   // 131056 rows

typedef __attribute__((ext_vector_type(8))) short short8;
typedef __attribute__((ext_vector_type(4))) float f32x4;
typedef __attribute__((ext_vector_type(4))) unsigned int u32x4;

static __device__ __forceinline__ unsigned short f2bf(float f) {
    unsigned u = __builtin_bit_cast(unsigned, f);
    u += 0x7FFFu + ((u >> 16) & 1u);   // RNE
    return (unsigned short)(u >> 16);
}

static __device__ __forceinline__ unsigned pk2(float lo, float hi) {
    __hip_bfloat162 t = __float22bfloat162_rn(float2{lo, hi});
    unsigned u;
    __builtin_memcpy(&u, &t, 4);
    return u;
}

// 8 f32 -> 8 bf16 (v_cvt_pk_bf16_f32)
static __device__ __forceinline__ short8 cvt8(const f32x4 a, const f32x4 b) {
    u32x4 uv;
    uv[0] = pk2(a[0], a[1]);
    uv[1] = pk2(a[2], a[3]);
    uv[2] = pk2(b[0], b[1]);
    uv[3] = pk2(b[2], b[3]);
    return __builtin_bit_cast(short8, uv);
}

// async global->LDS, 16B per lane
static __device__ __forceinline__ void gl2lds16(const void* g, unsigned char* l) {
    __builtin_amdgcn_global_load_lds(
        (const __attribute__((address_space(1))) void*)g,
        (__attribute__((address_space(3))) void*)l,
        16, 0, 0);
}

// ---- DPP row_ror reduces over 16-lane groups ----
template<int CTRL>
static __device__ __forceinline__ float dppf(float v) {
    return __builtin_bit_cast(float,
        __builtin_amdgcn_update_dpp(0, __builtin_bit_cast(int, v), CTRL, 0xF, 0xF, false));
}
template<int CTRL>
static __device__ __forceinline__ int dppi(int v) {
    return __builtin_amdgcn_update_dpp(0, v, CTRL, 0xF, 0xF, false);
}
static __device__ __forceinline__ float sum16f(float v) {
    v += dppf<0x121>(v); v += dppf<0x122>(v); v += dppf<0x124>(v); v += dppf<0x128>(v);
    return v;
}
static __device__ __forceinline__ float max16f(float v) {
    v = fmaxf(v, dppf<0x121>(v)); v = fmaxf(v, dppf<0x122>(v));
    v = fmaxf(v, dppf<0x124>(v)); v = fmaxf(v, dppf<0x128>(v));
    return v;
}
static __device__ __forceinline__ unsigned sum16u(unsigned v) {
    v += (unsigned)dppi<0x121>((int)v); v += (unsigned)dppi<0x122>((int)v);
    v += (unsigned)dppi<0x124>((int)v); v += (unsigned)dppi<0x128>((int)v);
    return v;
}

// ---------------- prep: W1 (E x H) -> W1T bf16 (H x E); W2 (H x M) -> W2T bf16 (M x H)
__global__ void prep_weights(const float* __restrict__ W1, const float* __restrict__ W2,
                             unsigned short* __restrict__ W1T, unsigned short* __restrict__ W2T)
{
    const int b = blockIdx.x, tid = threadIdx.x;
    if (b < 64) {
        const int e0 = b * 8, h = tid;
        short8 sv;
#pragma unroll
        for (int j = 0; j < 8; ++j)
            sv[j] = (short)f2bf(W1[(size_t)(e0 + j) * HH + h]);
        *(short8*)(void*)(W1T + (size_t)h * EE + e0) = sv;
    } else {
        const int h0 = (b - 64) * 16;
        if (tid < MM) {
            const int m = tid;
            short8 s0v, s1v;
#pragma unroll
            for (int j = 0; j < 8; ++j) {
                s0v[j] = (short)f2bf(W2[(size_t)(h0 + j) * MM + m]);
                s1v[j] = (short)f2bf(W2[(size_t)(h0 + 8 + j) * MM + m]);
            }
            *(short8*)(void*)(W2T + (size_t)m * HH + h0) = s0v;
            *(short8*)(void*)(W2T + (size_t)m * HH + h0 + 8) = s1v;
        }
    }
}

// ---------------- K1: clean-FIFO GEMM. 128 rows/block, 512 threads = 8 waves,
// each wave owns 16 rows. x: direct global->reg A-frags, depth-2 prefetch.
// W1T: chunked global->LDS dbuf (2x32KB) via gl2lds; consumed via lgkm ds_read only.
// Per chunk the ONLY vmcnt wait is a counted vmcnt(8) at the top.
__global__ __launch_bounds__(512, 4)
void gene_gemm_kernel(const float* __restrict__ x,
                      const unsigned short* __restrict__ W1T,
                      const float* __restrict__ b1,
                      const unsigned short* __restrict__ W2T,
                      float* __restrict__ logits)
{
    __shared__ __align__(16) unsigned char lds[65536];

    const int tid  = threadIdx.x;
    const int c    = blockIdx.y;
    const int s0   = blockIdx.x * 128;

    const int w    = tid >> 6;      // wave 0..7: rows s0 + w*16 .. +15
    const int lane = tid & 63;
    const int lr   = lane & 15;
    const int kq   = lane >> 4;
    const int s0w  = s0 + w * 16;
    unsigned char* slice = lds + w * 8192;   // wave-local h region (after GEMM1)

    // x A-frag source: lane -> row lr of the wave's 16; k-slice kq*8
    const int rowg = min(s0w + lr, SS - 1);
    const float* xrow = x + ((size_t)c * LL + 1 + rowg) * EE + kq * 8;

    // x prefetch sets: A = even chunks, B = odd chunks (4 f32x4 each)
    f32x4 xa0, xa1, xa2, xa3, xb0, xb1, xb2, xb3;
#define LOADXA(ck) do { const float* p_ = xrow + (ck) * 64;                   \
    xa0 = *(const f32x4*)p_;        xa1 = *(const f32x4*)(p_ + 4);            \
    xa2 = *(const f32x4*)(p_ + 32); xa3 = *(const f32x4*)(p_ + 36); } while (0)
#define LOADXB(ck) do { const float* p_ = xrow + (ck) * 64;                   \
    xb0 = *(const f32x4*)p_;        xb1 = *(const f32x4*)(p_ + 4);            \
    xb2 = *(const f32x4*)(p_ + 32); xb3 = *(const f32x4*)(p_ + 36); } while (0)

    // W chunk staging: 2048 units of 16B; unit u -> col=u>>3, subL=u&7;
    // content sub = subL ^ (col&7) (source-swizzled, linear dest)
#define STAGEW(ck, bo) do {                                                   \
    _Pragma("unroll")                                                         \
    for (int it_ = 0; it_ < 4; ++it_) {                                       \
        const int u_ = it_ * 512 + tid;                                       \
        const int col_ = u_ >> 3, subL_ = u_ & 7;                             \
        const unsigned short* g_ = W1T + (size_t)col_ * EE + (ck) * 64        \
                                   + ((subL_ ^ (col_ & 7)) << 3);             \
        gl2lds16(g_, lds + (bo) + u_ * 16);                                   \
    } } while (0)

    f32x4 acc[16];
#pragma unroll
    for (int n = 0; n < 16; ++n) acc[n] = (f32x4)0.0f;

    // prologue FIFO: x0, W0, x1, W1
    LOADXA(0);
    STAGEW(0, 0);
    LOADXB(1);
    STAGEW(1, 32768);
    __builtin_amdgcn_sched_barrier(0);

#define DO_CHUNK(J, V, X0, X1, X2, X3, RELOAD) do {                           \
    asm volatile("s_waitcnt vmcnt(" #V ")" ::: "memory");                     \
    asm volatile("s_waitcnt lgkmcnt(0)" ::: "memory");                        \
    __builtin_amdgcn_sched_barrier(0);                                        \
    __builtin_amdgcn_s_barrier();                                             \
    __builtin_amdgcn_sched_barrier(0);                                        \
    const short8 af0_ = cvt8(X0, X1);   /* ks=0 frag */                       \
    const short8 af1_ = cvt8(X2, X3);   /* ks=1 frag */                       \
    RELOAD;                            /* x(J+2) into the freed set */        \
    __builtin_amdgcn_sched_barrier(0);                                        \
    const unsigned char* wb_ = lds + (((J) & 1) << 15);                       \
    _Pragma("unroll")                                                         \
    for (int n_ = 0; n_ < 16; ++n_) {                                         \
        const int col_ = n_ * 16 + lr;                                        \
        const short8 wf0_ = *(const short8*)(const void*)                     \
            (wb_ + (((col_ << 3) + (kq ^ (col_ & 7))) << 4));                 \
        acc[n_] = __builtin_amdgcn_mfma_f32_16x16x32_bf16(af0_, wf0_, acc[n_], 0, 0, 0); \
    }                                                                         \
    _Pragma("unroll")                                                         \
    for (int n_ = 0; n_ < 16; ++n_) {                                         \
        const int col_ = n_ * 16 + lr;                                        \
        const short8 wf1_ = *(const short8*)(const void*)                     \
            (wb_ + (((col_ << 3) + ((4 + kq) ^ (col_ & 7))) << 4));           \
        acc[n_] = __builtin_amdgcn_mfma_f32_16x16x32_bf16(af1_, wf1_, acc[n_], 0, 0, 0); \
    }                                                                         \
    asm volatile("s_waitcnt lgkmcnt(0)" ::: "memory");                        \
    __builtin_amdgcn_sched_barrier(0);                                        \
    __builtin_amdgcn_s_barrier();   /* buf (J&1) reads done in all waves */   \
    __builtin_amdgcn_sched_barrier(0);                                        \
    if ((J) <= 5) STAGEW((J) + 2, ((J) & 1) << 15);                           \
    } while (0)

    DO_CHUNK(0, 8, xa0, xa1, xa2, xa3, LOADXA(2));
    DO_CHUNK(1, 8, xb0, xb1, xb2, xb3, LOADXB(3));
    DO_CHUNK(2, 8, xa0, xa1, xa2, xa3, LOADXA(4));
    DO_CHUNK(3, 8, xb0, xb1, xb2, xb3, LOADXB(5));
    DO_CHUNK(4, 8, xa0, xa1, xa2, xa3, LOADXA(6));
    DO_CHUNK(5, 8, xb0, xb1, xb2, xb3, LOADXB(7));
    DO_CHUNK(6, 8, xa0, xa1, xa2, xa3, (void)0);
    DO_CHUNK(7, 0, xb0, xb1, xb2, xb3, (void)0);

    // ---- bias + relu -> h bf16 wave-local [16][512B] swizzled (overlays W bufs) ----
#pragma unroll
    for (int n = 0; n < 16; ++n) {
        const float bb = b1[n * 16 + lr];
#pragma unroll
        for (int q = 0; q < 4; ++q) {
            const int row = kq * 4 + q;
            *(unsigned short*)(slice + row * 512 + (((n * 16 + lr) * 2) ^ ((row & 7) << 4))) =
                f2bf(fmaxf(acc[n][q] + bb, 0.0f));
        }
    }

    // ---- GEMM2: logits[16][128] = h @ W2 (wave-local; W2T global is L2-hot) ----
    const int rswz = (lr & 7) << 4;
    f32x4 acc2[8];
#pragma unroll
    for (int n = 0; n < 8; ++n) acc2[n] = (f32x4)0.0f;

#pragma unroll
    for (int ks = 0; ks < 8; ++ks) {
        const short8 ah = *(const short8*)(const void*)
            (slice + lr * 512 + ((ks * 64 + kq * 16) ^ rswz));
#pragma unroll
        for (int n = 0; n < 8; ++n) {
            const short8 bw = *(const short8*)(const void*)
                (W2T + (size_t)(n * 16 + lr) * HH + ks * 32 + kq * 8);
            acc2[n] = __builtin_amdgcn_mfma_f32_16x16x32_bf16(ah, bw, acc2[n], 0, 0, 0);
        }
    }

    // ---- direct global store of logits ----
#pragma unroll
    for (int n = 0; n < 8; ++n)
#pragma unroll
        for (int q = 0; q < 4; ++q) {
            const int s = s0w + kq * 4 + q;
            if (s < SS)
                logits[((size_t)c * SS + s) * MM + n * 16 + lr] = acc2[n][q];
        }
#undef DO_CHUNK
#undef STAGEW
#undef LOADXA
#undef LOADXB
}

// ---------------- K2: epilogue-only. Barrier-free, LDS-free. 64 rows/block, 256 thr.
__global__ __launch_bounds__(256, 8)
void gene_epi_kernel(const float* __restrict__ noise,
                     const int*   __restrict__ mask,
                     const float* __restrict__ b2,
                     float* __restrict__ out,
                     float* __restrict__ outk)
{
    const int tid = threadIdx.x;
    const int tx  = tid & 15;
    const int ty  = tid >> 4;
    const long base = (long)blockIdx.x * 64;

    if (tid < 64) {
        const long gr = base + tid;
        if (gr < TOT) {
            const int cc2 = (int)(gr / SS);
            outk[gr] = (mask[gr + cc2 + 1] != 0) ? 1.0f : 0.0f;
        }
    }

    float b2v[8];
    {
        const float4 bb0 = *(const float4*)(b2 + tx * 8 + 0);
        const float4 bb1 = *(const float4*)(b2 + tx * 8 + 4);
        b2v[0]=bb0.x; b2v[1]=bb0.y; b2v[2]=bb0.z; b2v[3]=bb0.w;
        b2v[4]=bb1.x; b2v[5]=bb1.y; b2v[6]=bb1.z; b2v[7]=bb1.w;
    }

    float pr[4][8];
    float pmaxv[4];
    float mz[4];
    long  grv[4];

#pragma unroll
    for (int i = 0; i < 4; ++i) {
        const long gr  = base + ty * 4 + i;
        grv[i] = gr;
        const long grc = gr < TOT ? gr : (TOT - 1);
        const int  cc2 = (int)(grc / SS);
        mz[i] = (mask[grc + cc2 + 1] != 0) ? 0.0f : 1.0f;

        const float* lp = out   + grc * MM + tx * 8;
        const float* np = noise + grc * MM + tx * 8;
        const float4 l0 = *(const float4*)lp;
        const float4 l1 = *(const float4*)(lp + 4);
        const float4 u0 = *(const float4*)np;
        const float4 u1 = *(const float4*)(np + 4);
        const float lg[8] = {l0.x,l0.y,l0.z,l0.w,l1.x,l1.y,l1.z,l1.w};
        const float uu[8] = {u0.x,u0.y,u0.z,u0.w,u1.x,u1.y,u1.z,u1.w};
        float pm[8];
#pragma unroll
        for (int q = 0; q < 8; ++q) {
            const float g = -__logf(-__logf(uu[q] + 1e-20f) + 1e-20f);
            pm[q] = lg[q] + b2v[q] + g;
        }
        float mx = pm[0];
#pragma unroll
        for (int q = 1; q < 8; ++q) mx = fmaxf(mx, pm[q]);
        mx = max16f(mx);
        float se = 0.0f;
#pragma unroll
        for (int q = 0; q < 8; ++q) { pr[i][q] = __expf(pm[q] - mx); se += pr[i][q]; }
        se = sum16f(se);
        const float inv = 1.0f / se;
#pragma unroll
        for (int q = 0; q < 8; ++q) pr[i][q] *= inv;
        pmaxv[i] = inv;
    }

    float lo[4], hi[4];
#pragma unroll
    for (int i = 0; i < 4; ++i) { lo[i] = 0.0f; hi[i] = fminf(pmaxv[i], 1.0f / 30.0f); }
    for (int it = 0; it < 10; ++it) {
        float mid[4];
#pragma unroll
        for (int i = 0; i < 4; ++i) mid[i] = 0.5f * (lo[i] + hi[i]);
        unsigned cnt = 0;
#pragma unroll
        for (int q = 0; q < 8; ++q) {
            cnt += (pr[0][q] > mid[0]) ? 1u : 0u;
            cnt += (pr[1][q] > mid[1]) ? (1u << 8) : 0u;
            cnt += (pr[2][q] > mid[2]) ? (1u << 16) : 0u;
            cnt += (pr[3][q] > mid[3]) ? (1u << 24) : 0u;
        }
        cnt = sum16u(cnt);
#pragma unroll
        for (int i = 0; i < 4; ++i) {
            const bool ge = ((cnt >> (8 * i)) & 255u) >= TOPK;
            lo[i] = ge ? mid[i] : lo[i];
            hi[i] = ge ? hi[i] : mid[i];
        }
    }

#pragma unroll
    for (int i = 0; i < 4; ++i) {
        if (grv[i] < TOT) {
            float ov[8];
#pragma unroll
            for (int q = 0; q < 8; ++q) {
                const float sm = 1.0f / (1.0f + __expf((hi[i] - pr[i][q]) * 100.0f));
                ov[q] = pr[i][q] * sm * mz[i];
            }
            float* op = out + grv[i] * MM + tx * 8;
            float4 o0, o1;
            o0.x=ov[0]; o0.y=ov[1]; o0.z=ov[2]; o0.w=ov[3];
            o1.x=ov[4]; o1.y=ov[5]; o1.z=ov[6]; o1.w=ov[7];
            *(float4*)(op + 0) = o0;
            *(float4*)(op + 4) = o1;
        }
    }
}

extern "C" void kernel_launch(void* const* d_in, const int* in_sizes, int n_in,
                              void* d_out, int out_size, void* d_ws, size_t ws_size,
                              hipStream_t stream) {
    const float* x     = (const float*)d_in[0];
    const int*   mask  = (const int*)d_in[1];
    const float* noise = (const float*)d_in[2];
    const float* W1    = (const float*)d_in[3];
    const float* b1    = (const float*)d_in[4];
    const float* W2    = (const float*)d_in[5];
    const float* b2    = (const float*)d_in[6];
    float* out  = (float*)d_out;
    float* outk = out + (size_t)CC * SS * MM;

    unsigned short* W1T = (unsigned short*)d_ws;            // 256 x 512 bf16 = 256 KB
    unsigned short* W2T = W1T + (size_t)HH * EE;            // 128 x 256 bf16 =  64 KB

    prep_weights<<<dim3(80), dim3(256), 0, stream>>>(W1, W2, W1T, W2T);

    gene_gemm_kernel<<<dim3(64, CC), dim3(512), 0, stream>>>(x, W1T, b1, W2T, out);

    const int nblk = (TOT + 63) / 64;   // 2048
    gene_epi_kernel<<<dim3(nblk), dim3(256), 0, stream>>>(noise, mask, b2, out, outk);
}